// Round 5
// baseline (198.785 us; speedup 1.0000x reference)
//
#include <hip/hip_runtime.h>
#include <stdint.h>

// BertSelfAttentionWithRelation  B=4 L=512 H=12 D=64 HIDDEN=768
// Round 5: concurrency-first k_rel.
//   phase A: rel-K scores via MFMA with B-fragments loaded DIRECTLY from
//            global (relk rows contiguous in d) -> no LDS, no barriers,
//            straight-line 8 tiles/wave with prefetch distance 2
//   phase B: S_rel via LDS (24KB, swizzled), wave-parallel softmax,
//            P written back IN PLACE as f32 (no separate ps buffer)
//   phase C: rel-V context on VALU: lane=d, coalesced f32 rows, P broadcast
//            float4 from LDS; cross-wave reduce reuses S_rel region
//   only 3 lgkmcnt-only barriers per block; vmcnt never force-drained.

typedef __attribute__((ext_vector_type(8))) short bf16x8;
typedef __attribute__((ext_vector_type(4))) float f32x4;
typedef __attribute__((ext_vector_type(4))) unsigned int u32x4;

__device__ __forceinline__ unsigned short f2bf(float f) {
  union { float f; unsigned int u; } v; v.f = f;
  unsigned int r = v.u + 0x7fffu + ((v.u >> 16) & 1u);
  return (unsigned short)(r >> 16);
}
__device__ __forceinline__ float bf2f(unsigned short s) {
  union { unsigned int u; float f; } v; v.u = ((unsigned int)s) << 16;
  return v.f;
}
// LDS-only barrier: cross-wave LDS visibility without draining vmcnt
__device__ __forceinline__ void lds_barrier() {
  asm volatile("s_waitcnt lgkmcnt(0)\ns_barrier" ::: "memory");
}

// ---------------- K0a: hidden fp32 -> bf16 ----------------
__global__ void k_cvt_hidden(const float* __restrict__ x, unsigned short* __restrict__ y) {
  int i = blockIdx.x * 256 + threadIdx.x;
  float4 v = reinterpret_cast<const float4*>(x)[i];
  ushort4 o;
  o.x = f2bf(v.x); o.y = f2bf(v.y); o.z = f2bf(v.z); o.w = f2bf(v.w);
  reinterpret_cast<ushort4*>(y)[i] = o;
}

// ---------------- K0b: W -> W^T concat bf16 ----------------
__global__ void k_transp_w(const float* __restrict__ Wq, const float* __restrict__ Wk,
                           const float* __restrict__ Wv, unsigned short* __restrict__ wt) {
  __shared__ float t[64][65];
  const int kt = blockIdx.x, nt = blockIdx.y, wsel = blockIdx.z;
  const float* W = wsel == 0 ? Wq : (wsel == 1 ? Wk : Wv);
  const int lx = threadIdx.x & 63, ly = threadIdx.x >> 6;
  for (int i = 0; i < 64; i += 4)
    t[ly + i][lx] = W[(size_t)(kt * 64 + ly + i) * 768 + nt * 64 + lx];
  __syncthreads();
  for (int i = 0; i < 64; i += 4) {
    int r = ly + i;
    wt[((size_t)wsel * 768 + nt * 64 + r) * 768 + kt * 64 + lx] = f2bf(t[lx][r]);
  }
}

// ---------------- K1: fused QKV GEMM (bf16 MFMA) ----------------
__global__ __launch_bounds__(256) void k_qkv_gemm(
    const unsigned short* __restrict__ A, const unsigned short* __restrict__ Bt,
    const float* __restrict__ bq, const float* __restrict__ bk, const float* __restrict__ bv,
    unsigned short* __restrict__ qbf, unsigned short* __restrict__ kbf,
    unsigned short* __restrict__ vbt) {
  __shared__ __align__(16) unsigned short lA[64 * 64];
  __shared__ __align__(16) unsigned short lB[64 * 64];
  const int tid = threadIdx.x, lane = tid & 63, w = tid >> 6;
  const int m0 = blockIdx.x * 64, n0 = blockIdx.y * 64;
  const int wm = (w >> 1) * 32, wn = (w & 1) * 32;
  f32x4 acc[2][2] = {};

  for (int kt = 0; kt < 12; ++kt) {
    __syncthreads();
#pragma unroll
    for (int i = 0; i < 2; ++i) {
      int e16 = i * 256 + tid;
      int row = e16 >> 3;
      int kb = (e16 & 7) * 16;
      int dst = row * 128 + (kb ^ ((row & 7) << 4));
      u32x4 va = *(const u32x4*)((const char*)A + (size_t)(m0 + row) * 1536 + kt * 128 + kb);
      *(u32x4*)((char*)lA + dst) = va;
      u32x4 vb = *(const u32x4*)((const char*)Bt + (size_t)(n0 + row) * 1536 + kt * 128 + kb);
      *(u32x4*)((char*)lB + dst) = vb;
    }
    __syncthreads();
#pragma unroll
    for (int ks = 0; ks < 2; ++ks) {
      bf16x8 fa[2], fb[2];
      const int kbyte = (ks * 32 + (lane >> 4) * 8) * 2;
#pragma unroll
      for (int mi = 0; mi < 2; ++mi) {
        int row = wm + mi * 16 + (lane & 15);
        fa[mi] = *(const bf16x8*)((const char*)lA + row * 128 + (kbyte ^ ((row & 7) << 4)));
      }
#pragma unroll
      for (int ni = 0; ni < 2; ++ni) {
        int row = wn + ni * 16 + (lane & 15);
        fb[ni] = *(const bf16x8*)((const char*)lB + row * 128 + (kbyte ^ ((row & 7) << 4)));
      }
#pragma unroll
      for (int mi = 0; mi < 2; ++mi)
#pragma unroll
        for (int ni = 0; ni < 2; ++ni)
          acc[mi][ni] = __builtin_amdgcn_mfma_f32_16x16x32_bf16(fa[mi], fb[ni], acc[mi][ni], 0, 0, 0);
    }
  }
#pragma unroll
  for (int mi = 0; mi < 2; ++mi)
#pragma unroll
    for (int ni = 0; ni < 2; ++ni) {
      int gn = n0 + wn + ni * 16 + (lane & 15);
      float bias = (gn < 768) ? bq[gn] : (gn < 1536 ? bk[gn - 768] : bv[gn - 1536]);
#pragma unroll
      for (int r = 0; r < 4; ++r) {
        int gm = m0 + wm + mi * 16 + ((lane >> 4) << 2) + r;
        float val = acc[mi][ni][r] + bias;
        int b = gm >> 9, l = gm & 511;
        int d = gn & 63;
        if (gn < 768) {
          int h = gn >> 6;
          qbf[(((size_t)(b * 12 + h)) * 512 + l) * 64 + d] = f2bf(val);
        } else if (gn < 1536) {
          int h = (gn - 768) >> 6;
          kbf[(((size_t)(b * 12 + h)) * 512 + l) * 64 + d] = f2bf(val);
        } else {
          int h = (gn - 1536) >> 6;
          vbt[(((size_t)(b * 12 + h)) * 64 + d) * 512 + l] = f2bf(val);
        }
      }
    }
}

// ---------------- K2a: content scores S = q.k^T per (b,h) ----------------
__global__ __launch_bounds__(256) void k_scores(
    const unsigned short* __restrict__ qbf, const unsigned short* __restrict__ kbf,
    float* __restrict__ S) {
  __shared__ __align__(16) unsigned short lQ[64 * 64];
  __shared__ __align__(16) unsigned short lK[64 * 64];
  const int tid = threadIdx.x, lane = tid & 63, w = tid >> 6;
  const int mt = blockIdx.x, lt = blockIdx.y, bh = blockIdx.z;
  const int wm = (w >> 1) * 32, wn = (w & 1) * 32;
  f32x4 acc[2][2] = {};
#pragma unroll
  for (int i = 0; i < 2; ++i) {
    int e16 = i * 256 + tid;
    int row = e16 >> 3;
    int kb = (e16 & 7) * 16;
    int dst = row * 128 + (kb ^ ((row & 7) << 4));
    u32x4 vq = *(const u32x4*)((const char*)qbf + ((size_t)bh * 512 + lt * 64 + row) * 128 + kb);
    *(u32x4*)((char*)lQ + dst) = vq;
    u32x4 vk = *(const u32x4*)((const char*)kbf + ((size_t)bh * 512 + mt * 64 + row) * 128 + kb);
    *(u32x4*)((char*)lK + dst) = vk;
  }
  __syncthreads();
#pragma unroll
  for (int ks = 0; ks < 2; ++ks) {
    bf16x8 fa[2], fb[2];
    const int kbyte = (ks * 32 + (lane >> 4) * 8) * 2;
#pragma unroll
    for (int mi = 0; mi < 2; ++mi) {
      int row = wm + mi * 16 + (lane & 15);
      fa[mi] = *(const bf16x8*)((const char*)lQ + row * 128 + (kbyte ^ ((row & 7) << 4)));
    }
#pragma unroll
    for (int ni = 0; ni < 2; ++ni) {
      int row = wn + ni * 16 + (lane & 15);
      fb[ni] = *(const bf16x8*)((const char*)lK + row * 128 + (kbyte ^ ((row & 7) << 4)));
    }
#pragma unroll
    for (int mi = 0; mi < 2; ++mi)
#pragma unroll
      for (int ni = 0; ni < 2; ++ni)
        acc[mi][ni] = __builtin_amdgcn_mfma_f32_16x16x32_bf16(fa[mi], fb[ni], acc[mi][ni], 0, 0, 0);
  }
#pragma unroll
  for (int mi = 0; mi < 2; ++mi)
#pragma unroll
    for (int ni = 0; ni < 2; ++ni) {
      int gm = mt * 64 + wn + ni * 16 + (lane & 15);
#pragma unroll
      for (int r = 0; r < 4; ++r) {
        int gl = lt * 64 + wm + mi * 16 + ((lane >> 4) << 2) + r;
        S[(size_t)bh * 262144 + (size_t)gl * 512 + gm] = acc[mi][ni][r];
      }
    }
}

// ---------------- K2b: fused relation kernel, one block per (b,l) ----------
__global__ __launch_bounds__(256) void k_rel(
    const unsigned short* __restrict__ qbf,
    const float* __restrict__ relk,   // [B][L][L][D]  (b, l, r, d)
    const float* __restrict__ relv,   // [B][L][L][D]  indexed (b, r, l, d)
    const float* __restrict__ S,
    unsigned short* __restrict__ pbf,
    float* __restrict__ crel) {
  // 24 KB: S_rel[12][512] f32 (swizzled) -> overwritten in place by P ->
  //        reused as red[4][12][64] after phase C
  __shared__ __align__(16) char X[24576];
  const int tid = threadIdx.x, lane = tid & 63, w = tid >> 6;
  const int bl = blockIdx.x, b = bl >> 9, l = bl & 511;
  const int lm = lane & 15, lg = lane >> 4;

  // q A-fragments (row h = lm, clamped; k-octet d = lg*8 / 32+lg*8)
  const int hq = lm < 12 ? lm : 11;
  const char* qrow = (const char*)qbf + (((size_t)b * 12 + hq) * 512 + l) * 128;
  const bf16x8 qa0 = *(const bf16x8*)(qrow + lg * 16);
  const bf16x8 qa1 = *(const bf16x8*)(qrow + 64 + lg * 16);

  // ---- phase A: rel-K scores via MFMA, direct-from-global B-fragments ----
  // wave w owns r in [w*128, w*128+128), 8 tiles of 16 rows; lane's row: +lm
  const char* rkb = (const char*)relk + (size_t)bl * 131072 +
                    (size_t)(w * 128 + lm) * 256 + lg * 32;
  f32x4 ld[3][4];
  f32x4 accA[8];
#pragma unroll
  for (int t = 0; t < 8; ++t) accA[t] = {0.f, 0.f, 0.f, 0.f};

#define LOADT(t, s)                                                  \
  {                                                                  \
    const char* p_ = rkb + (size_t)(t) * 4096;                       \
    ld[s][0] = *(const f32x4*)(p_);                                  \
    ld[s][1] = *(const f32x4*)(p_ + 16);                             \
    ld[s][2] = *(const f32x4*)(p_ + 128);                            \
    ld[s][3] = *(const f32x4*)(p_ + 144);                            \
  }
  LOADT(0, 0)
  LOADT(1, 1)
#pragma unroll
  for (int t = 0; t < 8; ++t) {
    if (t < 6) LOADT(t + 2, (t + 2) % 3)
    union { bf16x8 v; unsigned short u[8]; } fb0, fb1;
    const int s = t % 3;
#pragma unroll
    for (int j = 0; j < 4; ++j) {
      fb0.u[j] = f2bf(ld[s][0][j]);
      fb0.u[4 + j] = f2bf(ld[s][1][j]);
      fb1.u[j] = f2bf(ld[s][2][j]);
      fb1.u[4 + j] = f2bf(ld[s][3][j]);
    }
    accA[t] = __builtin_amdgcn_mfma_f32_16x16x32_bf16(qa0, fb0.v, accA[t], 0, 0, 0);
    accA[t] = __builtin_amdgcn_mfma_f32_16x16x32_bf16(qa1, fb1.v, accA[t], 0, 0, 0);
  }
#undef LOADT

  // content scores into regs (in flight across the S_rel staging barrier)
  float sreg[3][8];
#pragma unroll
  for (int hh = 0; hh < 3; ++hh) {
    const float* sp = S + (((size_t)b * 12 + (w * 3 + hh)) * 512 + l) * 512 + lane;
#pragma unroll
    for (int j = 0; j < 8; ++j) sreg[hh][j] = sp[j * 64];
  }

  // S_rel -> LDS. lane holds S_rel[h=lg*4+reg][r=w*128+t*16+lm], reg 0..3
  // swizzle: byte ^= ((h>>2)&3)<<6  (distinct per lg -> <=2-way write)
  if (lg < 3) {
#pragma unroll
    for (int t = 0; t < 8; ++t) {
      const int r = w * 128 + t * 16 + lm;
#pragma unroll
      for (int reg = 0; reg < 4; ++reg) {
        const int h = lg * 4 + reg;
        *(float*)(X + h * 2048 + ((r * 4) ^ (lg << 6))) = accA[t][reg];
      }
    }
  }
  lds_barrier();   // S_rel visible

  // ---- phase B: softmax, wave owns h = 3w..3w+2; P overwrites S_rel ----
#pragma unroll
  for (int hh = 0; hh < 3; ++hh) {
    const int h = w * 3 + hh;
    const int sw = ((h >> 2) & 3) << 6;
    const size_t srow = (((size_t)b * 12 + h) * 512 + l) * 512;
    float sv[8];
    float mx = -1e30f;
#pragma unroll
    for (int j = 0; j < 8; ++j) {
      const int r = j * 64 + lane;
      float s = (*(const float*)(X + h * 2048 + ((r * 4) ^ sw)) + sreg[hh][j]) * 0.125f;
      sv[j] = s;
      mx = fmaxf(mx, s);
    }
#pragma unroll
    for (int off = 32; off; off >>= 1) mx = fmaxf(mx, __shfl_xor(mx, off));
    float sm = 0.f;
#pragma unroll
    for (int j = 0; j < 8; ++j) { sv[j] = __expf(sv[j] - mx); sm += sv[j]; }
#pragma unroll
    for (int off = 32; off; off >>= 1) sm += __shfl_xor(sm, off);
    const float inv = 1.f / sm;
#pragma unroll
    for (int j = 0; j < 8; ++j) {
      const int r = j * 64 + lane;
      const float pv = sv[j] * inv;
      *(float*)(X + h * 2048 + ((r * 4) ^ sw)) = pv;       // P in place
      pbf[srow + r] = f2bf(pv);
    }
  }
  lds_barrier();   // P visible to all waves

  // ---- phase C: rel-V context on VALU. wave w: r in [w*128,+128); lane=d ----
  float cacc[12];
#pragma unroll
  for (int h = 0; h < 12; ++h) cacc[h] = 0.f;
  const char* vptr = (const char*)relv + (size_t)b * 67108864 +
                     (size_t)(w * 128) * 131072 + (size_t)l * 256 + lane * 4;
#pragma unroll 2
  for (int rc = 0; rc < 32; ++rc) {
    const float v0 = *(const float*)(vptr);
    const float v1 = *(const float*)(vptr + 131072);
    const float v2 = *(const float*)(vptr + 262144);
    const float v3 = *(const float*)(vptr + 393216);
    vptr += 524288;
    const int r0 = w * 128 + rc * 4;
#pragma unroll
    for (int h = 0; h < 12; ++h) {
      const f32x4 p = *(const f32x4*)(X + h * 2048 + ((r0 * 4) ^ (((h >> 2) & 3) << 6)));
      cacc[h] += p[0] * v0 + p[1] * v1 + p[2] * v2 + p[3] * v3;
    }
  }
  lds_barrier();   // all P reads done -> X reusable as red
  float* red = (float*)X;   // [4][12][64] = 12 KB
#pragma unroll
  for (int h = 0; h < 12; ++h) red[(w * 12 + h) * 64 + lane] = cacc[h];
  lds_barrier();
  for (int i = tid; i < 768; i += 256) {
    const int h = i >> 6, d = i & 63;
    crel[(size_t)bl * 768 + i] =
        red[h * 64 + d] + red[(12 + h) * 64 + d] + red[(24 + h) * 64 + d] + red[(36 + h) * 64 + d];
  }
}

// ---------------- K3: ctx = P@V per (b,h) via MFMA, + crel ----------------
__global__ __launch_bounds__(256) void k_pv(
    const unsigned short* __restrict__ pbf, const unsigned short* __restrict__ vbt,
    const float* __restrict__ crel, float* __restrict__ out) {
  __shared__ __align__(16) unsigned short lP[64 * 64];
  __shared__ __align__(16) unsigned short lV[64 * 64];
  const int tid = threadIdx.x, lane = tid & 63, w = tid >> 6;
  const int lt = blockIdx.x, bh = blockIdx.y;
  const int b = bh / 12, h = bh % 12;
  const int wm = (w >> 1) * 32, wn = (w & 1) * 32;
  f32x4 acc[2][2] = {};
  const char* pbase = (const char*)pbf + ((size_t)bh * 512 + lt * 64) * 1024;
  const char* vbase = (const char*)vbt + (size_t)bh * 64 * 1024;
  for (int kt = 0; kt < 8; ++kt) {
    __syncthreads();
#pragma unroll
    for (int i = 0; i < 2; ++i) {
      int e16 = i * 256 + tid;
      int row = e16 >> 3;
      int kb = (e16 & 7) * 16;
      int dst = row * 128 + (kb ^ ((row & 7) << 4));
      u32x4 vp = *(const u32x4*)(pbase + (size_t)row * 1024 + kt * 128 + kb);
      *(u32x4*)((char*)lP + dst) = vp;
      u32x4 vv = *(const u32x4*)(vbase + (size_t)row * 1024 + kt * 128 + kb);
      *(u32x4*)((char*)lV + dst) = vv;
    }
    __syncthreads();
#pragma unroll
    for (int ks = 0; ks < 2; ++ks) {
      bf16x8 fa[2], fb[2];
      const int kbyte = (ks * 32 + (lane >> 4) * 8) * 2;
#pragma unroll
      for (int mi = 0; mi < 2; ++mi) {
        int row = wm + mi * 16 + (lane & 15);
        fa[mi] = *(const bf16x8*)((const char*)lP + row * 128 + (kbyte ^ ((row & 7) << 4)));
      }
#pragma unroll
      for (int ni = 0; ni < 2; ++ni) {
        int row = wn + ni * 16 + (lane & 15);
        fb[ni] = *(const bf16x8*)((const char*)lV + row * 128 + (kbyte ^ ((row & 7) << 4)));
      }
#pragma unroll
      for (int mi = 0; mi < 2; ++mi)
#pragma unroll
        for (int ni = 0; ni < 2; ++ni)
          acc[mi][ni] = __builtin_amdgcn_mfma_f32_16x16x32_bf16(fa[mi], fb[ni], acc[mi][ni], 0, 0, 0);
    }
  }
#pragma unroll
  for (int mi = 0; mi < 2; ++mi)
#pragma unroll
    for (int ni = 0; ni < 2; ++ni) {
      int gd = wn + ni * 16 + (lane & 15);
#pragma unroll
      for (int r = 0; r < 4; ++r) {
        int gl = lt * 64 + wm + mi * 16 + ((lane >> 4) << 2) + r;
        size_t o = ((size_t)b * 512 + gl) * 768 + h * 64 + gd;
        out[o] = acc[mi][ni][r] + crel[o];
      }
    }
}

extern "C" void kernel_launch(void* const* d_in, const int* in_sizes, int n_in,
                              void* d_out, int out_size, void* d_ws, size_t ws_size,
                              hipStream_t stream) {
  (void)in_sizes; (void)n_in; (void)out_size; (void)ws_size;
  const float* hidden = (const float*)d_in[0];
  const float* relk   = (const float*)d_in[1];
  const float* relv   = (const float*)d_in[2];
  const float* Wq     = (const float*)d_in[3];
  const float* bq     = (const float*)d_in[4];
  const float* Wk     = (const float*)d_in[5];
  const float* bk     = (const float*)d_in[6];
  const float* Wv     = (const float*)d_in[7];
  const float* bv     = (const float*)d_in[8];
  float* out = (float*)d_out;
  char* ws = (char*)d_ws;

  unsigned short* hb  = (unsigned short*)(ws);
  unsigned short* wt  = (unsigned short*)(ws + 3145728);
  unsigned short* qbf = (unsigned short*)(ws + 6684672);
  unsigned short* kbf = (unsigned short*)(ws + 9830400);
  unsigned short* vbt = (unsigned short*)(ws + 12976128);
  float*          S   = (float*)(ws + 16121856);
  unsigned short* pbf = (unsigned short*)(ws + 66453504);
  float*          cr  = (float*)(ws + 91619328);

  k_cvt_hidden<<<1536, 256, 0, stream>>>(hidden, hb);
  k_transp_w<<<dim3(12, 12, 3), 256, 0, stream>>>(Wq, Wk, Wv, wt);
  k_qkv_gemm<<<dim3(32, 36), 256, 0, stream>>>(hb, wt, bq, bk, bv, qbf, kbf, vbt);
  k_scores<<<dim3(8, 8, 48), 256, 0, stream>>>(qbf, kbf, S);
  k_rel<<<2048, 256, 0, stream>>>(qbf, relk, relv, S, pbf, cr);
  k_pv<<<dim3(8, 48), 256, 0, stream>>>(pbf, vbt, cr, out);
}

// Round 6
// 194.628 us; speedup vs baseline: 1.0214x; 1.0214x over previous
//
#include <hip/hip_runtime.h>
#include <stdint.h>

// BertSelfAttentionWithRelation  B=4 L=512 H=12 D=64 HIDDEN=768
// Round 6: counted-vmcnt inline-asm pipeline in k_rel (T3/T4 port).
//   All k_rel global loads are asm volatile global_load_* issued in explicit
//   batches; s_waitcnt vmcnt(N) counted (never 0 mid-loop); sched_barrier(0)
//   after every wait (rule #18). Compiler cannot serialize the stream.
//   phase A: relk MFMA, 3-slot tile pipeline, 12 loads in flight
//   phase B: in-register softmax (S content preloaded in phase-A queue)
//   phase C: relv VALU stream, 8-row batches, 24 loads in flight
//   epilogue: pbf write-back from LDS P, then red-overlay reduce -> crel

typedef __attribute__((ext_vector_type(8))) short bf16x8;
typedef __attribute__((ext_vector_type(4))) float f32x4;
typedef __attribute__((ext_vector_type(4))) unsigned int u32x4;

__device__ __forceinline__ unsigned short f2bf(float f) {
  union { float f; unsigned int u; } v; v.f = f;
  unsigned int r = v.u + 0x7fffu + ((v.u >> 16) & 1u);
  return (unsigned short)(r >> 16);
}
__device__ __forceinline__ float bf2f(unsigned short s) {
  union { unsigned int u; float f; } v; v.u = ((unsigned int)s) << 16;
  return v.f;
}
__device__ __forceinline__ void lds_barrier() {
  asm volatile("s_waitcnt lgkmcnt(0)\ns_barrier" ::: "memory");
}
__device__ __forceinline__ unsigned cvtpk(float lo, float hi) {
  unsigned r;
  asm("v_cvt_pk_bf16_f32 %0, %1, %2" : "=v"(r) : "v"(lo), "v"(hi));
  return r;
}

#define GL16(dst, addr, OFF)                                                  \
  asm volatile("global_load_dwordx4 %0, %1, off offset:" #OFF                \
               : "=v"(dst) : "v"(addr))
#define GL4(dst, addr, OFF)                                                   \
  asm volatile("global_load_dword %0, %1, off offset:" #OFF                  \
               : "=v"(dst) : "v"(addr))
#define WAITV(N)                                                              \
  do {                                                                        \
    asm volatile("s_waitcnt vmcnt(" #N ")" ::: "memory");                     \
    __builtin_amdgcn_sched_barrier(0);                                        \
  } while (0)

// ---------------- K0a: hidden fp32 -> bf16 ----------------
__global__ void k_cvt_hidden(const float* __restrict__ x, unsigned short* __restrict__ y) {
  int i = blockIdx.x * 256 + threadIdx.x;
  float4 v = reinterpret_cast<const float4*>(x)[i];
  ushort4 o;
  o.x = f2bf(v.x); o.y = f2bf(v.y); o.z = f2bf(v.z); o.w = f2bf(v.w);
  reinterpret_cast<ushort4*>(y)[i] = o;
}

// ---------------- K0b: W -> W^T concat bf16 ----------------
__global__ void k_transp_w(const float* __restrict__ Wq, const float* __restrict__ Wk,
                           const float* __restrict__ Wv, unsigned short* __restrict__ wt) {
  __shared__ float t[64][65];
  const int kt = blockIdx.x, nt = blockIdx.y, wsel = blockIdx.z;
  const float* W = wsel == 0 ? Wq : (wsel == 1 ? Wk : Wv);
  const int lx = threadIdx.x & 63, ly = threadIdx.x >> 6;
  for (int i = 0; i < 64; i += 4)
    t[ly + i][lx] = W[(size_t)(kt * 64 + ly + i) * 768 + nt * 64 + lx];
  __syncthreads();
  for (int i = 0; i < 64; i += 4) {
    int r = ly + i;
    wt[((size_t)wsel * 768 + nt * 64 + r) * 768 + kt * 64 + lx] = f2bf(t[lx][r]);
  }
}

// ---------------- K1: fused QKV GEMM (bf16 MFMA) ----------------
__global__ __launch_bounds__(256) void k_qkv_gemm(
    const unsigned short* __restrict__ A, const unsigned short* __restrict__ Bt,
    const float* __restrict__ bq, const float* __restrict__ bk, const float* __restrict__ bv,
    unsigned short* __restrict__ qbf, unsigned short* __restrict__ kbf,
    unsigned short* __restrict__ vbt) {
  __shared__ __align__(16) unsigned short lA[64 * 64];
  __shared__ __align__(16) unsigned short lB[64 * 64];
  const int tid = threadIdx.x, lane = tid & 63, w = tid >> 6;
  const int m0 = blockIdx.x * 64, n0 = blockIdx.y * 64;
  const int wm = (w >> 1) * 32, wn = (w & 1) * 32;
  f32x4 acc[2][2] = {};

  for (int kt = 0; kt < 12; ++kt) {
    __syncthreads();
#pragma unroll
    for (int i = 0; i < 2; ++i) {
      int e16 = i * 256 + tid;
      int row = e16 >> 3;
      int kb = (e16 & 7) * 16;
      int dst = row * 128 + (kb ^ ((row & 7) << 4));
      u32x4 va = *(const u32x4*)((const char*)A + (size_t)(m0 + row) * 1536 + kt * 128 + kb);
      *(u32x4*)((char*)lA + dst) = va;
      u32x4 vb = *(const u32x4*)((const char*)Bt + (size_t)(n0 + row) * 1536 + kt * 128 + kb);
      *(u32x4*)((char*)lB + dst) = vb;
    }
    __syncthreads();
#pragma unroll
    for (int ks = 0; ks < 2; ++ks) {
      bf16x8 fa[2], fb[2];
      const int kbyte = (ks * 32 + (lane >> 4) * 8) * 2;
#pragma unroll
      for (int mi = 0; mi < 2; ++mi) {
        int row = wm + mi * 16 + (lane & 15);
        fa[mi] = *(const bf16x8*)((const char*)lA + row * 128 + (kbyte ^ ((row & 7) << 4)));
      }
#pragma unroll
      for (int ni = 0; ni < 2; ++ni) {
        int row = wn + ni * 16 + (lane & 15);
        fb[ni] = *(const bf16x8*)((const char*)lB + row * 128 + (kbyte ^ ((row & 7) << 4)));
      }
#pragma unroll
      for (int mi = 0; mi < 2; ++mi)
#pragma unroll
        for (int ni = 0; ni < 2; ++ni)
          acc[mi][ni] = __builtin_amdgcn_mfma_f32_16x16x32_bf16(fa[mi], fb[ni], acc[mi][ni], 0, 0, 0);
    }
  }
#pragma unroll
  for (int mi = 0; mi < 2; ++mi)
#pragma unroll
    for (int ni = 0; ni < 2; ++ni) {
      int gn = n0 + wn + ni * 16 + (lane & 15);
      float bias = (gn < 768) ? bq[gn] : (gn < 1536 ? bk[gn - 768] : bv[gn - 1536]);
#pragma unroll
      for (int r = 0; r < 4; ++r) {
        int gm = m0 + wm + mi * 16 + ((lane >> 4) << 2) + r;
        float val = acc[mi][ni][r] + bias;
        int b = gm >> 9, l = gm & 511;
        int d = gn & 63;
        if (gn < 768) {
          int h = gn >> 6;
          qbf[(((size_t)(b * 12 + h)) * 512 + l) * 64 + d] = f2bf(val);
        } else if (gn < 1536) {
          int h = (gn - 768) >> 6;
          kbf[(((size_t)(b * 12 + h)) * 512 + l) * 64 + d] = f2bf(val);
        } else {
          int h = (gn - 1536) >> 6;
          vbt[(((size_t)(b * 12 + h)) * 64 + d) * 512 + l] = f2bf(val);
        }
      }
    }
}

// ---------------- K2a: content scores S = q.k^T per (b,h) ----------------
__global__ __launch_bounds__(256) void k_scores(
    const unsigned short* __restrict__ qbf, const unsigned short* __restrict__ kbf,
    float* __restrict__ S) {
  __shared__ __align__(16) unsigned short lQ[64 * 64];
  __shared__ __align__(16) unsigned short lK[64 * 64];
  const int tid = threadIdx.x, lane = tid & 63, w = tid >> 6;
  const int mt = blockIdx.x, lt = blockIdx.y, bh = blockIdx.z;
  const int wm = (w >> 1) * 32, wn = (w & 1) * 32;
  f32x4 acc[2][2] = {};
#pragma unroll
  for (int i = 0; i < 2; ++i) {
    int e16 = i * 256 + tid;
    int row = e16 >> 3;
    int kb = (e16 & 7) * 16;
    int dst = row * 128 + (kb ^ ((row & 7) << 4));
    u32x4 vq = *(const u32x4*)((const char*)qbf + ((size_t)bh * 512 + lt * 64 + row) * 128 + kb);
    *(u32x4*)((char*)lQ + dst) = vq;
    u32x4 vk = *(const u32x4*)((const char*)kbf + ((size_t)bh * 512 + mt * 64 + row) * 128 + kb);
    *(u32x4*)((char*)lK + dst) = vk;
  }
  __syncthreads();
#pragma unroll
  for (int ks = 0; ks < 2; ++ks) {
    bf16x8 fa[2], fb[2];
    const int kbyte = (ks * 32 + (lane >> 4) * 8) * 2;
#pragma unroll
    for (int mi = 0; mi < 2; ++mi) {
      int row = wm + mi * 16 + (lane & 15);
      fa[mi] = *(const bf16x8*)((const char*)lQ + row * 128 + (kbyte ^ ((row & 7) << 4)));
    }
#pragma unroll
    for (int ni = 0; ni < 2; ++ni) {
      int row = wn + ni * 16 + (lane & 15);
      fb[ni] = *(const bf16x8*)((const char*)lK + row * 128 + (kbyte ^ ((row & 7) << 4)));
    }
#pragma unroll
    for (int mi = 0; mi < 2; ++mi)
#pragma unroll
      for (int ni = 0; ni < 2; ++ni)
        acc[mi][ni] = __builtin_amdgcn_mfma_f32_16x16x32_bf16(fa[mi], fb[ni], acc[mi][ni], 0, 0, 0);
  }
#pragma unroll
  for (int mi = 0; mi < 2; ++mi)
#pragma unroll
    for (int ni = 0; ni < 2; ++ni) {
      int gm = mt * 64 + wn + ni * 16 + (lane & 15);
#pragma unroll
      for (int r = 0; r < 4; ++r) {
        int gl = lt * 64 + wm + mi * 16 + ((lane >> 4) << 2) + r;
        S[(size_t)bh * 262144 + (size_t)gl * 512 + gm] = acc[mi][ni][r];
      }
    }
}

// ---------------- K2b: fused relation kernel, counted-vmcnt pipeline ------
__global__ __launch_bounds__(256) void k_rel(
    const unsigned short* __restrict__ qbf,
    const float* __restrict__ relk,   // [B][L][L][D]  (b, l, r, d)
    const float* __restrict__ relv,   // [B][L][L][D]  indexed (b, r, l, d)
    const float* __restrict__ S,
    unsigned short* __restrict__ pbf,
    float* __restrict__ crel) {
  __shared__ __align__(16) char X[24576];   // S_rel/P [12][512] f32 swizzled
  const int tid = threadIdx.x, lane = tid & 63, w = tid >> 6;
  const int bl = blockIdx.x, b = bl >> 9, l = bl & 511;
  const int lm = lane & 15, lg = lane >> 4;
  const int hq = lm < 12 ? lm : 11;

  // ---- issue phase-A queue: qa(2), sreg(24), tiles 0..1 (8) ----
  union { f32x4 f; bf16x8 b; } qa0, qa1;
  const char* aQ = (const char*)qbf + (((size_t)b * 12 + hq) * 512 + l) * 128 + (size_t)lg * 16;
  GL16(qa0.f, aQ, 0);
  GL16(qa1.f, aQ, 64);

  float sreg[3][8];
  const char* aS = (const char*)S + ((((size_t)b * 12 + w * 3) * 512 + l) * 512 + lane) * 4;
#define SRLOAD(hh)                                                            \
  do {                                                                        \
    const char* p_ = aS + (size_t)(hh) * 1048576;                             \
    GL4(sreg[hh][0], p_, 0);    GL4(sreg[hh][1], p_, 256);                    \
    GL4(sreg[hh][2], p_, 512);  GL4(sreg[hh][3], p_, 768);                    \
    GL4(sreg[hh][4], p_, 1024); GL4(sreg[hh][5], p_, 1280);                   \
    GL4(sreg[hh][6], p_, 1536); GL4(sreg[hh][7], p_, 1792);                   \
  } while (0)
  SRLOAD(0); SRLOAD(1); SRLOAD(2);

  const char* aA = (const char*)relk + (size_t)bl * 131072 +
                   (size_t)(w * 128 + lm) * 256 + (size_t)lg * 32;
  f32x4 td[3][4];
#define TISSUE(t, s)                                                          \
  do {                                                                        \
    const char* p_ = aA + (size_t)(t) * 4096;                                 \
    GL16(td[s][0], p_, 0);   GL16(td[s][1], p_, 16);                          \
    GL16(td[s][2], p_, 128); GL16(td[s][3], p_, 144);                         \
  } while (0)
  TISSUE(0, 0);
  TISSUE(1, 1);

  // consume tile t (slot s): pack bf16, 2 MFMA, write S_rel slice to LDS
#define ACONSUME(t, s)                                                        \
  do {                                                                        \
    union { bf16x8 v; unsigned u[4]; } fb0, fb1;                              \
    fb0.u[0] = cvtpk(td[s][0][0], td[s][0][1]);                               \
    fb0.u[1] = cvtpk(td[s][0][2], td[s][0][3]);                               \
    fb0.u[2] = cvtpk(td[s][1][0], td[s][1][1]);                               \
    fb0.u[3] = cvtpk(td[s][1][2], td[s][1][3]);                               \
    fb1.u[0] = cvtpk(td[s][2][0], td[s][2][1]);                               \
    fb1.u[1] = cvtpk(td[s][2][2], td[s][2][3]);                               \
    fb1.u[2] = cvtpk(td[s][3][0], td[s][3][1]);                               \
    fb1.u[3] = cvtpk(td[s][3][2], td[s][3][3]);                               \
    f32x4 acc = {0.f, 0.f, 0.f, 0.f};                                         \
    acc = __builtin_amdgcn_mfma_f32_16x16x32_bf16(qa0.b, fb0.v, acc, 0, 0, 0);\
    acc = __builtin_amdgcn_mfma_f32_16x16x32_bf16(qa1.b, fb1.v, acc, 0, 0, 0);\
    if (lg < 3) {                                                             \
      const int r_ = w * 128 + (t) * 16 + lm;                                 \
      _Pragma("unroll")                                                       \
      for (int reg = 0; reg < 4; ++reg)                                       \
        *(float*)(X + (lg * 4 + reg) * 2048 + ((r_ * 4) ^ (lg << 6))) =       \
            acc[reg];                                                         \
    }                                                                         \
  } while (0)

  TISSUE(2, 2); WAITV(8); ACONSUME(0, 0);
  TISSUE(3, 0); WAITV(8); ACONSUME(1, 1);
  TISSUE(4, 1); WAITV(8); ACONSUME(2, 2);
  TISSUE(5, 2); WAITV(8); ACONSUME(3, 0);
  TISSUE(6, 0); WAITV(8); ACONSUME(4, 1);
  TISSUE(7, 1); WAITV(8); ACONSUME(5, 2);
  WAITV(4); ACONSUME(6, 0);
  WAITV(0); ACONSUME(7, 1);

  lds_barrier();   // S_rel visible

  // ---- phase B: softmax; wave owns h = 3w..3w+2; P overwrites S_rel ----
#pragma unroll
  for (int hh = 0; hh < 3; ++hh) {
    const int h = w * 3 + hh;
    const int sw = ((h >> 2) & 3) << 6;
    float sv[8];
    float mx = -1e30f;
#pragma unroll
    for (int j = 0; j < 8; ++j) {
      const int r = j * 64 + lane;
      float s = (*(const float*)(X + h * 2048 + ((r * 4) ^ sw)) + sreg[hh][j]) * 0.125f;
      sv[j] = s;
      mx = fmaxf(mx, s);
    }
#pragma unroll
    for (int off = 32; off; off >>= 1) mx = fmaxf(mx, __shfl_xor(mx, off));
    float sm = 0.f;
#pragma unroll
    for (int j = 0; j < 8; ++j) { sv[j] = __expf(sv[j] - mx); sm += sv[j]; }
#pragma unroll
    for (int off = 32; off; off >>= 1) sm += __shfl_xor(sm, off);
    const float inv = 1.f / sm;
#pragma unroll
    for (int j = 0; j < 8; ++j) {
      const int r = j * 64 + lane;
      *(float*)(X + h * 2048 + ((r * 4) ^ sw)) = sv[j] * inv;
    }
  }
  lds_barrier();   // P visible

  // ---- phase C: relv stream, 8-row batches, 24 loads in flight ----
  const char* aV[8];
#pragma unroll
  for (int j = 0; j < 8; ++j)
    aV[j] = (const char*)relv + (size_t)b * 67108864 +
            (size_t)(w * 128 + j) * 131072 + (size_t)l * 256 + (size_t)lane * 4;
  float vv[3][8];
#define CISSUE(m, s)                                                          \
  do {                                                                        \
    GL4(vv[s][0], aV[0] + (size_t)(m) * 1048576, 0);                          \
    GL4(vv[s][1], aV[1] + (size_t)(m) * 1048576, 0);                          \
    GL4(vv[s][2], aV[2] + (size_t)(m) * 1048576, 0);                          \
    GL4(vv[s][3], aV[3] + (size_t)(m) * 1048576, 0);                          \
    GL4(vv[s][4], aV[4] + (size_t)(m) * 1048576, 0);                          \
    GL4(vv[s][5], aV[5] + (size_t)(m) * 1048576, 0);                          \
    GL4(vv[s][6], aV[6] + (size_t)(m) * 1048576, 0);                          \
    GL4(vv[s][7], aV[7] + (size_t)(m) * 1048576, 0);                          \
  } while (0)

  float cacc[12];
#pragma unroll
  for (int h = 0; h < 12; ++h) cacc[h] = 0.f;

#define CCONSUME(g, s)                                                        \
  do {                                                                        \
    _Pragma("unroll")                                                         \
    for (int q = 0; q < 2; ++q) {                                             \
      const int rb = w * 512 + (g) * 32 + q * 16;                             \
      _Pragma("unroll")                                                       \
      for (int h = 0; h < 12; ++h) {                                          \
        const f32x4 p =                                                       \
            *(const f32x4*)(X + h * 2048 + (rb ^ (((h >> 2) & 3) << 6)));     \
        cacc[h] += p[0] * vv[s][q * 4 + 0] + p[1] * vv[s][q * 4 + 1] +        \
                   p[2] * vv[s][q * 4 + 2] + p[3] * vv[s][q * 4 + 3];         \
      }                                                                       \
    }                                                                         \
  } while (0)

  CISSUE(0, 0);
  CISSUE(1, 1);
  CISSUE(2, 2);  WAITV(16); CCONSUME(0, 0);
  CISSUE(3, 0);  WAITV(16); CCONSUME(1, 1);
  CISSUE(4, 1);  WAITV(16); CCONSUME(2, 2);
  CISSUE(5, 2);  WAITV(16); CCONSUME(3, 0);
  CISSUE(6, 0);  WAITV(16); CCONSUME(4, 1);
  CISSUE(7, 1);  WAITV(16); CCONSUME(5, 2);
  CISSUE(8, 2);  WAITV(16); CCONSUME(6, 0);
  CISSUE(9, 0);  WAITV(16); CCONSUME(7, 1);
  CISSUE(10, 1); WAITV(16); CCONSUME(8, 2);
  CISSUE(11, 2); WAITV(16); CCONSUME(9, 0);
  CISSUE(12, 0); WAITV(16); CCONSUME(10, 1);
  CISSUE(13, 1); WAITV(16); CCONSUME(11, 2);
  CISSUE(14, 2); WAITV(16); CCONSUME(12, 0);
  CISSUE(15, 0); WAITV(16); CCONSUME(13, 1);
  WAITV(8);  CCONSUME(14, 2);
  WAITV(0);  CCONSUME(15, 0);

  lds_barrier();   // all P reads done

  // ---- epilogue 1: pbf write-back from LDS P ----
#pragma unroll
  for (int hh = 0; hh < 3; ++hh) {
    const int h = w * 3 + hh;
    const int sw = ((h >> 2) & 3) << 6;
    const size_t srow = (((size_t)b * 12 + h) * 512 + l) * 512;
#pragma unroll
    for (int j = 0; j < 8; ++j) {
      const int r = j * 64 + lane;
      pbf[srow + r] = f2bf(*(const float*)(X + h * 2048 + ((r * 4) ^ sw)));
    }
  }
  lds_barrier();   // pbf reads of X done -> overlay safe

  // ---- epilogue 2: cross-wave reduce -> crel ----
  float* red = (float*)X;   // [4][12][64] = 12 KB
#pragma unroll
  for (int h = 0; h < 12; ++h) red[(w * 12 + h) * 64 + lane] = cacc[h];
  lds_barrier();
  for (int i = tid; i < 768; i += 256) {
    const int h = i >> 6, d = i & 63;
    crel[(size_t)bl * 768 + i] =
        red[h * 64 + d] + red[(12 + h) * 64 + d] + red[(24 + h) * 64 + d] + red[(36 + h) * 64 + d];
  }
#undef SRLOAD
#undef TISSUE
#undef ACONSUME
#undef CISSUE
#undef CCONSUME
}

// ---------------- K3: ctx = P@V per (b,h) via MFMA, + crel ----------------
__global__ __launch_bounds__(256) void k_pv(
    const unsigned short* __restrict__ pbf, const unsigned short* __restrict__ vbt,
    const float* __restrict__ crel, float* __restrict__ out) {
  __shared__ __align__(16) unsigned short lP[64 * 64];
  __shared__ __align__(16) unsigned short lV[64 * 64];
  const int tid = threadIdx.x, lane = tid & 63, w = tid >> 6;
  const int lt = blockIdx.x, bh = blockIdx.y;
  const int b = bh / 12, h = bh % 12;
  const int wm = (w >> 1) * 32, wn = (w & 1) * 32;
  f32x4 acc[2][2] = {};
  const char* pbase = (const char*)pbf + ((size_t)bh * 512 + lt * 64) * 1024;
  const char* vbase = (const char*)vbt + (size_t)bh * 64 * 1024;
  for (int kt = 0; kt < 8; ++kt) {
    __syncthreads();
#pragma unroll
    for (int i = 0; i < 2; ++i) {
      int e16 = i * 256 + tid;
      int row = e16 >> 3;
      int kb = (e16 & 7) * 16;
      int dst = row * 128 + (kb ^ ((row & 7) << 4));
      u32x4 vp = *(const u32x4*)(pbase + (size_t)row * 1024 + kt * 128 + kb);
      *(u32x4*)((char*)lP + dst) = vp;
      u32x4 vv = *(const u32x4*)(vbase + (size_t)row * 1024 + kt * 128 + kb);
      *(u32x4*)((char*)lV + dst) = vv;
    }
    __syncthreads();
#pragma unroll
    for (int ks = 0; ks < 2; ++ks) {
      bf16x8 fa[2], fb[2];
      const int kbyte = (ks * 32 + (lane >> 4) * 8) * 2;
#pragma unroll
      for (int mi = 0; mi < 2; ++mi) {
        int row = wm + mi * 16 + (lane & 15);
        fa[mi] = *(const bf16x8*)((const char*)lP + row * 128 + (kbyte ^ ((row & 7) << 4)));
      }
#pragma unroll
      for (int ni = 0; ni < 2; ++ni) {
        int row = wn + ni * 16 + (lane & 15);
        fb[ni] = *(const bf16x8*)((const char*)lV + row * 128 + (kbyte ^ ((row & 7) << 4)));
      }
#pragma unroll
      for (int mi = 0; mi < 2; ++mi)
#pragma unroll
        for (int ni = 0; ni < 2; ++ni)
          acc[mi][ni] = __builtin_amdgcn_mfma_f32_16x16x32_bf16(fa[mi], fb[ni], acc[mi][ni], 0, 0, 0);
    }
  }
#pragma unroll
  for (int mi = 0; mi < 2; ++mi)
#pragma unroll
    for (int ni = 0; ni < 2; ++ni) {
      int gd = wn + ni * 16 + (lane & 15);
#pragma unroll
      for (int r = 0; r < 4; ++r) {
        int gl = lt * 64 + wm + mi * 16 + ((lane >> 4) << 2) + r;
        size_t o = ((size_t)b * 512 + gl) * 768 + h * 64 + gd;
        out[o] = acc[mi][ni][r] + crel[o];
      }
    }
}

extern "C" void kernel_launch(void* const* d_in, const int* in_sizes, int n_in,
                              void* d_out, int out_size, void* d_ws, size_t ws_size,
                              hipStream_t stream) {
  (void)in_sizes; (void)n_in; (void)out_size; (void)ws_size;
  const float* hidden = (const float*)d_in[0];
  const float* relk   = (const float*)d_in[1];
  const float* relv   = (const float*)d_in[2];
  const float* Wq     = (const float*)d_in[3];
  const float* bq     = (const float*)d_in[4];
  const float* Wk     = (const float*)d_in[5];
  const float* bk     = (const float*)d_in[6];
  const float* Wv     = (const float*)d_in[7];
  const float* bv     = (const float*)d_in[8];
  float* out = (float*)d_out;
  char* ws = (char*)d_ws;

  unsigned short* hb  = (unsigned short*)(ws);
  unsigned short* wt  = (unsigned short*)(ws + 3145728);
  unsigned short* qbf = (unsigned short*)(ws + 6684672);
  unsigned short* kbf = (unsigned short*)(ws + 9830400);
  unsigned short* vbt = (unsigned short*)(ws + 12976128);
  float*          S   = (float*)(ws + 16121856);
  unsigned short* pbf = (unsigned short*)(ws + 66453504);
  float*          cr  = (float*)(ws + 91619328);

  k_cvt_hidden<<<1536, 256, 0, stream>>>(hidden, hb);
  k_transp_w<<<dim3(12, 12, 3), 256, 0, stream>>>(Wq, Wk, Wv, wt);
  k_qkv_gemm<<<dim3(32, 36), 256, 0, stream>>>(hb, wt, bq, bk, bv, qbf, kbf, vbt);
  k_scores<<<dim3(8, 8, 48), 256, 0, stream>>>(qbf, kbf, S);
  k_rel<<<2048, 256, 0, stream>>>(qbf, relk, relv, S, pbf, cr);
  k_pv<<<dim3(8, 48), 256, 0, stream>>>(pbf, vbt, cr, out);
}